// Round 1
// baseline (129844.055 us; speedup 1.0000x reference)
//
#include <hip/hip_runtime.h>
#include <math.h>

#define NB 8
#define NT 1024
#define ND 128
#define NS 8
#define NH 4
#define NDH 32
#define NOUT 32000

__device__ __forceinline__ float sigm(float x) { return 1.0f / (1.0f + expf(-x)); }
__device__ __forceinline__ float dot4(float4 a, float4 b) {
    return a.x * b.x + a.y * b.y + a.z * b.z + a.w * b.w;
}

// Kernel 1: embedding gather + precompute x-half of z/r/h gate preactivations (incl. bias)
// xproj[bt][3][128]:  xz = xe@Wz[:,D:].T + bz,  xr, xh
__global__ __launch_bounds__(128) void k_embed_xproj(
    const int* __restrict__ x, const float* __restrict__ emb,
    const float* __restrict__ Wz, const float* __restrict__ bz,
    const float* __restrict__ Wr, const float* __restrict__ br,
    const float* __restrict__ Wh, const float* __restrict__ bh,
    float* __restrict__ xproj) {
    int bt = blockIdx.x;
    int j = threadIdx.x;
    __shared__ float xe[ND];
    long tok = (long)x[bt];
    xe[j] = emb[tok * ND + j];
    __syncthreads();
    const float4* xe4 = (const float4*)xe;
    const float4* wz = (const float4*)(Wz + j * 2 * ND + ND);
    const float4* wr = (const float4*)(Wr + j * 2 * ND + ND);
    const float4* wh = (const float4*)(Wh + j * 2 * ND + ND);
    float az = bz[j], ar = br[j], ah = bh[j];
#pragma unroll 8
    for (int k = 0; k < ND / 4; ++k) {
        float4 xv = xe4[k];
        az += dot4(wz[k], xv);
        ar += dot4(wr[k], xv);
        ah += dot4(wh[k], xv);
    }
    float* o = xproj + (long)bt * 3 * ND;
    o[j] = az;
    o[ND + j] = ar;
    o[2 * ND + j] = ah;
}

// Kernel 2: the sequential scan. One block per batch. 512 threads (8 waves).
__global__ __launch_bounds__(512) void k_scan(
    const float* __restrict__ xproj, const float* __restrict__ init_states,
    const float* __restrict__ Wz, const float* __restrict__ Wr, const float* __restrict__ Wh,
    const float* __restrict__ Wq, const float* __restrict__ bq,
    const float* __restrict__ Wk, const float* __restrict__ bk,
    const float* __restrict__ Wv, const float* __restrict__ bv,
    const float* __restrict__ Wo, const float* __restrict__ bo,
    const float* __restrict__ Wc, const float* __restrict__ bc,
    float* __restrict__ stout) {
    int b = blockIdx.x;
    int tid = threadIdx.x;
    __shared__ float st[NS][ND];   // current states
    __shared__ float rs[NS][ND];   // r*states; later reused for attention o
    __shared__ float nw[NS][ND];   // new (post-GRU)
    __shared__ float at[NS][ND];   // attn output (post Wo)
    __shared__ float qq[NS][ND], kk[NS][ND], vv[NS][ND];
    __shared__ float sc[NH][NS][NS];  // attention scores

    for (int idx = tid; idx < NS * ND; idx += 512)
        st[idx >> 7][idx & 127] = init_states[idx];
    __syncthreads();

    const float scale = 0.17677669529663687f;  // 1/sqrt(32)

    for (int t = 0; t < NT; ++t) {
        const float* xp = xproj + (long)(b * NT + t) * 3 * ND;
        float zreg[2];
        // Phase A: z (reg) and r*states (LDS)
#pragma unroll
        for (int it = 0; it < 2; ++it) {
            int idx = tid + it * 512;
            int s = idx >> 7, j = idx & 127;
            float az = xp[j], ar = xp[ND + j];
            const float4* wz = (const float4*)(Wz + j * 2 * ND);
            const float4* wr = (const float4*)(Wr + j * 2 * ND);
            const float4* sp = (const float4*)st[s];
#pragma unroll 8
            for (int k = 0; k < ND / 4; ++k) {
                float4 sv = sp[k];
                az += dot4(wz[k], sv);
                ar += dot4(wr[k], sv);
            }
            zreg[it] = sigm(az);
            float r = sigm(ar);
            rs[s][j] = r * st[s][j];
        }
        __syncthreads();
        // Phase B: cand = tanh(rs @ Wh_s.T + xh), new = (1-z)st + z*cand
#pragma unroll
        for (int it = 0; it < 2; ++it) {
            int idx = tid + it * 512;
            int s = idx >> 7, j = idx & 127;
            float ah = xp[2 * ND + j];
            const float4* wh = (const float4*)(Wh + j * 2 * ND);
            const float4* rp = (const float4*)rs[s];
#pragma unroll 8
            for (int k = 0; k < ND / 4; ++k) ah += dot4(wh[k], rp[k]);
            float cand = tanhf(ah);
            float z = zreg[it];
            nw[s][j] = (1.0f - z) * st[s][j] + z * cand;
        }
        __syncthreads();
        // Phase C: q, k, v projections of new
#pragma unroll
        for (int m = 0; m < 6; ++m) {
            int idx = tid + m * 512;
            int which = idx >> 10;
            int rem = idx & 1023;
            int s = rem >> 7, j = rem & 127;
            const float* Wp = (which == 0) ? Wq : (which == 1) ? Wk : Wv;
            const float* bp = (which == 0) ? bq : (which == 1) ? bk : bv;
            float acc = bp[j];
            const float4* wp = (const float4*)(Wp + j * ND);
            const float4* np = (const float4*)nw[s];
#pragma unroll 8
            for (int k = 0; k < ND / 4; ++k) acc += dot4(wp[k], np[k]);
            float(*dst)[ND] = (which == 0) ? qq : (which == 1) ? kk : vv;
            dst[s][j] = acc;
        }
        __syncthreads();
        // Phase D: scores[h][qs][ks]
        if (tid < 256) {
            int h = tid >> 6, qs = (tid >> 3) & 7, ks = tid & 7;
            float acc = 0.0f;
#pragma unroll
            for (int d = 0; d < NDH; ++d) acc += qq[qs][h * NDH + d] * kk[ks][h * NDH + d];
            sc[h][qs][ks] = acc * scale;
        }
        __syncthreads();
        // Phase E: softmax over ks
        if (tid < 32) {
            int h = tid >> 3, qs = tid & 7;
            float m = -1e30f;
#pragma unroll
            for (int ks = 0; ks < NS; ++ks) m = fmaxf(m, sc[h][qs][ks]);
            float sum = 0.0f;
#pragma unroll
            for (int ks = 0; ks < NS; ++ks) {
                float e = expf(sc[h][qs][ks] - m);
                sc[h][qs][ks] = e;
                sum += e;
            }
            float inv = 1.0f / sum;
#pragma unroll
            for (int ks = 0; ks < NS; ++ks) sc[h][qs][ks] *= inv;
        }
        __syncthreads();
        // Phase F: o = att @ v  (into rs, which is free now)
#pragma unroll
        for (int it = 0; it < 2; ++it) {
            int idx = tid + it * 512;
            int s = idx >> 7, j = idx & 127;
            int h = j >> 5;
            float acc = 0.0f;
#pragma unroll
            for (int ks = 0; ks < NS; ++ks) acc += sc[h][s][ks] * vv[ks][j];
            rs[s][j] = acc;
        }
        __syncthreads();
        // Phase G: at = o @ Wo.T + bo
#pragma unroll
        for (int it = 0; it < 2; ++it) {
            int idx = tid + it * 512;
            int s = idx >> 7, j = idx & 127;
            float acc = bo[j];
            const float4* wp = (const float4*)(Wo + j * ND);
            const float4* op = (const float4*)rs[s];
#pragma unroll 8
            for (int k = 0; k < ND / 4; ++k) acc += dot4(wp[k], op[k]);
            at[s][j] = acc;
        }
        __syncthreads();
        // Phase H: g = sigmoid([new, at] @ Wc.T + bc); st = g*new + (1-g)*at
#pragma unroll
        for (int it = 0; it < 2; ++it) {
            int idx = tid + it * 512;
            int s = idx >> 7, j = idx & 127;
            float acc = bc[j];
            const float4* wc1 = (const float4*)(Wc + j * 2 * ND);
            const float4* wc2 = (const float4*)(Wc + j * 2 * ND + ND);
            const float4* np = (const float4*)nw[s];
            const float4* ap = (const float4*)at[s];
#pragma unroll 8
            for (int k = 0; k < ND / 4; ++k) {
                acc += dot4(wc1[k], np[k]);
                acc += dot4(wc2[k], ap[k]);
            }
            float g = sigm(acc);
            st[s][j] = g * nw[s][j] + (1.0f - g) * at[s][j];
        }
        __syncthreads();
    }
    for (int idx = tid; idx < NS * ND; idx += 512)
        stout[(long)b * NS * ND + idx] = st[idx >> 7][idx & 127];
}

// Kernel 3: out[b][o] = stflat[b] . Wout[o] + bout[o].  One wave per output row.
__global__ __launch_bounds__(512) void k_out(
    const float* __restrict__ stflat, const float* __restrict__ Wout,
    const float* __restrict__ bout, float* __restrict__ out) {
    __shared__ float stl[NB][NS * ND];
    int tid = threadIdx.x;
    for (int idx = tid; idx < NB * NS * ND; idx += 512)
        stl[idx >> 10][idx & 1023] = stflat[idx];
    __syncthreads();
    int wave = tid >> 6, lane = tid & 63;
    int o = blockIdx.x * 8 + wave;
    float acc[NB];
#pragma unroll
    for (int b = 0; b < NB; ++b) acc[b] = 0.0f;
    const float4* wrow = (const float4*)(Wout + (size_t)o * (NS * ND));
#pragma unroll
    for (int i = 0; i < 4; ++i) {
        float4 w = wrow[i * 64 + lane];
        int kb = (i * 64 + lane) * 4;
#pragma unroll
        for (int b = 0; b < NB; ++b) {
            float4 sv = *(const float4*)&stl[b][kb];
            acc[b] += dot4(w, sv);
        }
    }
#pragma unroll
    for (int off = 32; off; off >>= 1) {
#pragma unroll
        for (int b = 0; b < NB; ++b) acc[b] += __shfl_down(acc[b], off);
    }
    if (lane == 0) {
        float bb = bout[o];
#pragma unroll
        for (int b = 0; b < NB; ++b) out[(size_t)b * NOUT + o] = acc[b] + bb;
    }
}

extern "C" void kernel_launch(void* const* d_in, const int* in_sizes, int n_in,
                              void* d_out, int out_size, void* d_ws, size_t ws_size,
                              hipStream_t stream) {
    const int* x = (const int*)d_in[0];
    const float* emb = (const float*)d_in[1];
    const float* init_states = (const float*)d_in[2];
    const float* Wz = (const float*)d_in[3];
    const float* bz = (const float*)d_in[4];
    const float* Wr = (const float*)d_in[5];
    const float* br = (const float*)d_in[6];
    const float* Wh = (const float*)d_in[7];
    const float* bh = (const float*)d_in[8];
    const float* Wq = (const float*)d_in[9];
    const float* bq = (const float*)d_in[10];
    const float* Wk = (const float*)d_in[11];
    const float* bk = (const float*)d_in[12];
    const float* Wv = (const float*)d_in[13];
    const float* bv = (const float*)d_in[14];
    const float* Wo = (const float*)d_in[15];
    const float* bo = (const float*)d_in[16];
    const float* Wc = (const float*)d_in[17];
    const float* bc = (const float*)d_in[18];
    const float* Wout = (const float*)d_in[19];
    const float* bout = (const float*)d_in[20];
    float* out = (float*)d_out;

    float* xproj = (float*)d_ws;                        // NB*NT*3*ND floats = 12.58 MB
    float* stflat = xproj + (size_t)NB * NT * 3 * ND;   // NB*NS*ND floats = 32 KB

    k_embed_xproj<<<NB * NT, 128, 0, stream>>>(x, emb, Wz, bz, Wr, br, Wh, bh, xproj);
    k_scan<<<NB, 512, 0, stream>>>(xproj, init_states, Wz, Wr, Wh, Wq, bq, Wk, bk, Wv, bv,
                                   Wo, bo, Wc, bc, stflat);
    k_out<<<NOUT / 8, 512, 0, stream>>>(stflat, Wout, bout, out);
}

// Round 2
// 12970.627 us; speedup vs baseline: 10.0106x; 10.0106x over previous
//
#include <hip/hip_runtime.h>
#include <math.h>

#define NB 8
#define NT 1024
#define ND 128
#define NS 8
#define NH 4
#define NOUT 32000

typedef _Float16 f16x8 __attribute__((ext_vector_type(8)));
typedef _Float16 f16x4 __attribute__((ext_vector_type(4)));
typedef float f32x4 __attribute__((ext_vector_type(4)));

__device__ __forceinline__ float sigm(float x) { return 1.0f / (1.0f + expf(-x)); }
__device__ __forceinline__ float dot4(float4 a, float4 b) {
    return a.x * b.x + a.y * b.y + a.z * b.z + a.w * b.w;
}

// ---------------------------------------------------------------------------
// Kernel 0: pack the 9 weight matrices (state-side halves) into MFMA B-frag
// order as dual-fp16 (hi + lo*2^11).  Matrix m, frag f=(nt*4+kt)*2+pl,
// thread t=(w*64+lane): value = W[col][k], col=32w+nt*16+(lane&15),
// k = kt*32+8*(lane>>4)+i.  64 KB per matrix, 576 KB total (L2-resident).
// mats: 0 Wz_s, 1 Wr_s, 2 Wh_s, 3 Wq, 4 Wk, 5 Wv, 6 Wc_new, 7 Wo, 8 Wc_attn
// ---------------------------------------------------------------------------
__global__ __launch_bounds__(256) void k_pack(
    const float* __restrict__ Wz, const float* __restrict__ Wr, const float* __restrict__ Wh,
    const float* __restrict__ Wq, const float* __restrict__ Wk, const float* __restrict__ Wv,
    const float* __restrict__ Wo, const float* __restrict__ Wc, _Float16* __restrict__ wpack) {
    int linear = blockIdx.x * 256 + threadIdx.x;   // m*4096 + f*256 + t
    int m = linear >> 12;
    int f = (linear >> 8) & 15;
    int t = linear & 255;
    int nt = f >> 3, kt = (f >> 1) & 3, pl = f & 1;
    int w = t >> 6, lane = t & 63;
    int col = 32 * w + nt * 16 + (lane & 15);
    int kk = kt * 32 + 8 * (lane >> 4);
    const float* src;
    int stride, koff = 0;
    switch (m) {
        case 0: src = Wz; stride = 256; break;
        case 1: src = Wr; stride = 256; break;
        case 2: src = Wh; stride = 256; break;
        case 3: src = Wq; stride = 128; break;
        case 4: src = Wk; stride = 128; break;
        case 5: src = Wv; stride = 128; break;
        case 6: src = Wc; stride = 256; break;            // c1 (new part)
        case 7: src = Wo; stride = 128; break;
        default: src = Wc; stride = 256; koff = 128; break; // c2 (attn part)
    }
    const float* p = src + (size_t)col * stride + koff + kk;
    f16x8 out;
#pragma unroll
    for (int i = 0; i < 8; ++i) {
        float v = p[i];
        _Float16 h = (_Float16)v;
        out[i] = pl ? (_Float16)((v - (float)h) * 2048.0f) : h;
    }
    *(f16x8*)(wpack + (size_t)linear * 8) = out;
}

// ---------------------------------------------------------------------------
// Kernel 1: embedding gather + x-half of z/r/h gate preactivations (+bias)
// ---------------------------------------------------------------------------
__global__ __launch_bounds__(128) void k_embed_xproj(
    const int* __restrict__ x, const float* __restrict__ emb,
    const float* __restrict__ Wz, const float* __restrict__ bz,
    const float* __restrict__ Wr, const float* __restrict__ br,
    const float* __restrict__ Wh, const float* __restrict__ bh,
    float* __restrict__ xproj) {
    int bt = blockIdx.x;
    int j = threadIdx.x;
    __shared__ float xe[ND];
    long tok = (long)x[bt];
    xe[j] = emb[tok * ND + j];
    __syncthreads();
    const float4* xe4 = (const float4*)xe;
    const float4* wz = (const float4*)(Wz + j * 2 * ND + ND);
    const float4* wr = (const float4*)(Wr + j * 2 * ND + ND);
    const float4* wh = (const float4*)(Wh + j * 2 * ND + ND);
    float az = bz[j], ar = br[j], ah = bh[j];
#pragma unroll 8
    for (int k = 0; k < ND / 4; ++k) {
        float4 xv = xe4[k];
        az += dot4(wz[k], xv);
        ar += dot4(wr[k], xv);
        ah += dot4(wh[k], xv);
    }
    float* o = xproj + (long)bt * 3 * ND;
    o[j] = az;
    o[ND + j] = ar;
    o[2 * ND + j] = ah;
}

// ---------------------------------------------------------------------------
// Kernel 2: the scan.  1 block/batch, 256 threads (4 waves).
// Wave w owns output cols 32w..32w+31 (2 MFMA N-tiles) of every matmul and
// attention head w.  Weights z,r,h register-resident; q,k,v,c1,o,c2 streamed
// from L2 each step (double-buffered).  Dual-fp16 Markidis split everywhere;
// attention core in fp32 VALU.
// ---------------------------------------------------------------------------
__global__ __launch_bounds__(256, 1) void k_scan(
    const float* __restrict__ xproj, const float* __restrict__ init_states,
    const _Float16* __restrict__ wpack,
    const float* __restrict__ bq, const float* __restrict__ bk, const float* __restrict__ bv,
    const float* __restrict__ bo, const float* __restrict__ bc,
    float* __restrict__ stout) {
    const int b = blockIdx.x, tid = threadIdx.x;
    const int lane = tid & 63, w = tid >> 6;
    const int lrow = lane & 15, lkb = lane >> 4;
    const int col0 = 32 * w + lrow, col1 = col0 + 16;
    const bool vrow = (lkb < 2);  // C rows 4*lkb+i < 8 are the real states

    __shared__ float stf[NS][132];                 // fp32 state (padded stride)
    __shared__ float qf[NS][132], kf[NS][132], vf[NS][132];
    __shared__ float pf[NH][NS][NS];
    // fp16 planes [16][128], XOR-swizzled; rows 8..15 stay zero (M-padding).
    // 0 st_h,1 st_l,2 rs_h,3 rs_l,4 nw_h,5 nw_l,6 at_h,7 at_l,8 ao_h,9 ao_l
    __shared__ _Float16 hp[10][16 * 128];

    for (int i = tid; i < 10 * 2048; i += 256) ((_Float16*)hp)[i] = (_Float16)0.0f;
    for (int i = tid; i < NS * ND; i += 256) {
        int s = i >> 7, d = i & 127;
        float v = init_states[i];
        stf[s][d] = v;
        _Float16 h = (_Float16)v;
        _Float16 l = (_Float16)((v - (float)h) * 2048.0f);
        int off = (s * 256 + d * 2) ^ ((s & 7) << 4);
        *(_Float16*)((char*)hp[0] + off) = h;
        *(_Float16*)((char*)hp[1] + off) = l;
    }

#define LOADW(BH, BL, m)                                                           \
    {                                                                              \
        const _Float16* base_ = wpack + (size_t)(m)*4096 * 8;                      \
        _Pragma("unroll") for (int nt_ = 0; nt_ < 2; ++nt_)                        \
        _Pragma("unroll") for (int kt_ = 0; kt_ < 4; ++kt_) {                      \
            BH[nt_][kt_] = *(const f16x8*)(base_ + (((nt_ * 4 + kt_) * 2 + 0) * 256 + tid) * 8); \
            BL[nt_][kt_] = *(const f16x8*)(base_ + (((nt_ * 4 + kt_) * 2 + 1) * 256 + tid) * 8); \
        }                                                                          \
    }

#define LDA(ph, pl_)                                                               \
    {                                                                              \
        _Pragma("unroll") for (int kt_ = 0; kt_ < 4; ++kt_) {                      \
            int off_ = (lrow * 256 + kt_ * 64 + lkb * 16) ^ ((lrow & 7) << 4);     \
            ah[kt_] = *(const f16x8*)((const char*)(ph) + off_);                   \
            al[kt_] = *(const f16x8*)((const char*)(pl_) + off_);                  \
        }                                                                          \
    }

#define MM(res, BH, BL, i0, i1)                                                    \
    {                                                                              \
        _Pragma("unroll") for (int nt_ = 0; nt_ < 2; ++nt_) {                      \
            float init_ = nt_ ? (i1) : (i0);                                       \
            f32x4 xh_ = {init_, init_, init_, init_};                              \
            f32x4 xl_ = {0.f, 0.f, 0.f, 0.f};                                      \
            _Pragma("unroll") for (int kt_ = 0; kt_ < 4; ++kt_) {                  \
                xh_ = __builtin_amdgcn_mfma_f32_16x16x32_f16(ah[kt_], BH[nt_][kt_], xh_, 0, 0, 0); \
                xl_ = __builtin_amdgcn_mfma_f32_16x16x32_f16(al[kt_], BH[nt_][kt_], xl_, 0, 0, 0); \
                xl_ = __builtin_amdgcn_mfma_f32_16x16x32_f16(ah[kt_], BL[nt_][kt_], xl_, 0, 0, 0); \
            }                                                                      \
            _Pragma("unroll") for (int i_ = 0; i_ < 4; ++i_)                       \
                res[nt_][i_] = xh_[i_] + xl_[i_] * 4.8828125e-4f;                  \
        }                                                                          \
    }

#define WRHL(pih, pil, row_, col_, val_)                                           \
    {                                                                              \
        float v_ = (val_);                                                         \
        _Float16 h_ = (_Float16)v_;                                                \
        _Float16 l_ = (_Float16)((v_ - (float)h_) * 2048.0f);                      \
        int off_ = ((row_)*256 + (col_)*2) ^ (((row_)&7) << 4);                    \
        *(_Float16*)((char*)hp[pih] + off_) = h_;                                  \
        *(_Float16*)((char*)hp[pil] + off_) = l_;                                  \
    }

    // resident weights: z, r, h (192 VGPRs)
    f16x8 Bzh[2][4], Bzl[2][4], Brh[2][4], Brl[2][4], Bhh[2][4], Bhl[2][4];
    LOADW(Bzh, Bzl, 0);
    LOADW(Brh, Brl, 1);
    LOADW(Bhh, Bhl, 2);
    const float bqv0 = bq[col0], bqv1 = bq[col1];
    const float bkv0 = bk[col0], bkv1 = bk[col1];
    const float bvv0 = bv[col0], bvv1 = bv[col1];
    const float bov0 = bo[col0], bov1 = bo[col1];
    const float bcv0 = bc[col0], bcv1 = bc[col1];

    f16x8 ah[4], al[4];
    f16x8 S0h[2][4], S0l[2][4], S1h[2][4], S1l[2][4];
    float zv[2][4], nwv[2][4], oval[2][4], stv[2][4];

    __syncthreads();

    for (int t = 0; t < NT; ++t) {
        const float* xp = xproj + ((size_t)(b * NT + t)) * 3 * ND;
        float xz0 = xp[col0], xz1 = xp[col1];
        float xr0 = xp[128 + col0], xr1 = xp[128 + col1];
        float xh0 = xp[256 + col0], xh1 = xp[256 + col1];
        LOADW(S0h, S0l, 3);  // stream Q
        // ---- ZR ----
        LDA(hp[0], hp[1]);
        float zp[2][4], rp[2][4];
        MM(zp, Bzh, Bzl, xz0, xz1);
        MM(rp, Brh, Brl, xr0, xr1);
        LOADW(S1h, S1l, 4);  // stream K
#pragma unroll
        for (int nt_ = 0; nt_ < 2; ++nt_)
#pragma unroll
            for (int i_ = 0; i_ < 4; ++i_) zv[nt_][i_] = sigm(zp[nt_][i_]);
        if (vrow) {
#pragma unroll
            for (int nt_ = 0; nt_ < 2; ++nt_) {
                int c_ = nt_ ? col1 : col0;
#pragma unroll
                for (int i_ = 0; i_ < 4; ++i_) {
                    int r_ = lkb * 4 + i_;
                    stv[nt_][i_] = stf[r_][c_];
                    float rs_ = sigm(rp[nt_][i_]) * stv[nt_][i_];
                    WRHL(2, 3, r_, c_, rs_);
                }
            }
        }
        __syncthreads();
        // ---- H (cand/new) ----
        LDA(hp[2], hp[3]);
        float hpre[2][4];
        MM(hpre, Bhh, Bhl, xh0, xh1);
        if (vrow) {
#pragma unroll
            for (int nt_ = 0; nt_ < 2; ++nt_) {
                int c_ = nt_ ? col1 : col0;
#pragma unroll
                for (int i_ = 0; i_ < 4; ++i_) {
                    int r_ = lkb * 4 + i_;
                    float cand = tanhf(hpre[nt_][i_]);
                    float nv = (1.0f - zv[nt_][i_]) * stv[nt_][i_] + zv[nt_][i_] * cand;
                    nwv[nt_][i_] = nv;
                    WRHL(4, 5, r_, c_, nv);
                }
            }
        }
        __syncthreads();
        // ---- QKV + C1 ----
        LDA(hp[4], hp[5]);
        f32x4 ach[2], acl[2];
        {
            float qp_[2][4];
            MM(qp_, S0h, S0l, bqv0, bqv1);
            if (vrow) {
#pragma unroll
                for (int nt_ = 0; nt_ < 2; ++nt_) {
                    int c_ = nt_ ? col1 : col0;
#pragma unroll
                    for (int i_ = 0; i_ < 4; ++i_) qf[lkb * 4 + i_][c_] = qp_[nt_][i_];
                }
            }
            LOADW(S0h, S0l, 5);  // stream V
            float kp_[2][4];
            MM(kp_, S1h, S1l, bkv0, bkv1);
            if (vrow) {
#pragma unroll
                for (int nt_ = 0; nt_ < 2; ++nt_) {
                    int c_ = nt_ ? col1 : col0;
#pragma unroll
                    for (int i_ = 0; i_ < 4; ++i_) kf[lkb * 4 + i_][c_] = kp_[nt_][i_];
                }
            }
            LOADW(S1h, S1l, 6);  // stream C1
            float vp_[2][4];
            MM(vp_, S0h, S0l, bvv0, bvv1);
            if (vrow) {
#pragma unroll
                for (int nt_ = 0; nt_ < 2; ++nt_) {
                    int c_ = nt_ ? col1 : col0;
#pragma unroll
                    for (int i_ = 0; i_ < 4; ++i_) vf[lkb * 4 + i_][c_] = vp_[nt_][i_];
                }
            }
            LOADW(S0h, S0l, 7);  // stream O
            // c1 accumulate (carried to C2 phase)
#pragma unroll
            for (int nt_ = 0; nt_ < 2; ++nt_) {
                float init_ = nt_ ? bcv1 : bcv0;
                ach[nt_] = (f32x4){init_, init_, init_, init_};
                acl[nt_] = (f32x4){0.f, 0.f, 0.f, 0.f};
#pragma unroll
                for (int kt_ = 0; kt_ < 4; ++kt_) {
                    ach[nt_] = __builtin_amdgcn_mfma_f32_16x16x32_f16(ah[kt_], S1h[nt_][kt_], ach[nt_], 0, 0, 0);
                    acl[nt_] = __builtin_amdgcn_mfma_f32_16x16x32_f16(al[kt_], S1h[nt_][kt_], acl[nt_], 0, 0, 0);
                    acl[nt_] = __builtin_amdgcn_mfma_f32_16x16x32_f16(ah[kt_], S1l[nt_][kt_], acl[nt_], 0, 0, 0);
                }
            }
            LOADW(S1h, S1l, 8);  // stream C2
        }
        __syncthreads();
        // ---- attention scores + softmax (wave w == head w), fp32 VALU ----
        {
            int sq = lane >> 3, skv = lane & 7;
            float s_ = 0.f;
#pragma unroll
            for (int j = 0; j < 8; ++j) {
                float4 qv = *(const float4*)&qf[sq][32 * w + 4 * j];
                float4 kv4 = *(const float4*)&kf[skv][32 * w + 4 * j];
                s_ += dot4(qv, kv4);
            }
            s_ *= 0.17677669529663687f;
            float mx = s_;
            mx = fmaxf(mx, __shfl_xor(mx, 1));
            mx = fmaxf(mx, __shfl_xor(mx, 2));
            mx = fmaxf(mx, __shfl_xor(mx, 4));
            float e_ = expf(s_ - mx);
            float sm = e_;
            sm += __shfl_xor(sm, 1);
            sm += __shfl_xor(sm, 2);
            sm += __shfl_xor(sm, 4);
            pf[w][sq][skv] = e_ / sm;
        }
        __syncthreads();
        // ---- PV: att = p @ v  -> at planes (dual fp16) ----
        {
            int pq = lane >> 3, dq = lane & 7;
            int dcol = 32 * w + dq * 4;
            float avx = 0.f, avy = 0.f, avz = 0.f, avw = 0.f;
#pragma unroll
            for (int kv2 = 0; kv2 < 8; ++kv2) {
                float pp = pf[w][pq][kv2];
                float4 vv4 = *(const float4*)&vf[kv2][dcol];
                avx += pp * vv4.x;
                avy += pp * vv4.y;
                avz += pp * vv4.z;
                avw += pp * vv4.w;
            }
            float vals[4] = {avx, avy, avz, avw};
            f16x4 hv, lv;
#pragma unroll
            for (int i_ = 0; i_ < 4; ++i_) {
                _Float16 h_ = (_Float16)vals[i_];
                hv[i_] = h_;
                lv[i_] = (_Float16)((vals[i_] - (float)h_) * 2048.0f);
            }
            int off_ = (pq * 256 + dcol * 2) ^ ((pq & 7) << 4);
            *(f16x4*)((char*)hp[6] + off_) = hv;
            *(f16x4*)((char*)hp[7] + off_) = lv;
        }
        __syncthreads();
        // ---- O projection ----
        LDA(hp[6], hp[7]);
        MM(oval, S0h, S0l, bov0, bov1);
        if (vrow) {
#pragma unroll
            for (int nt_ = 0; nt_ < 2; ++nt_) {
                int c_ = nt_ ? col1 : col0;
#pragma unroll
                for (int i_ = 0; i_ < 4; ++i_) WRHL(8, 9, lkb * 4 + i_, c_, oval[nt_][i_]);
            }
        }
        __syncthreads();
        // ---- C2 + gate blend -> new state ----
        LDA(hp[8], hp[9]);
#pragma unroll
        for (int nt_ = 0; nt_ < 2; ++nt_)
#pragma unroll
            for (int kt_ = 0; kt_ < 4; ++kt_) {
                ach[nt_] = __builtin_amdgcn_mfma_f32_16x16x32_f16(ah[kt_], S1h[nt_][kt_], ach[nt_], 0, 0, 0);
                acl[nt_] = __builtin_amdgcn_mfma_f32_16x16x32_f16(al[kt_], S1h[nt_][kt_], acl[nt_], 0, 0, 0);
                acl[nt_] = __builtin_amdgcn_mfma_f32_16x16x32_f16(ah[kt_], S1l[nt_][kt_], acl[nt_], 0, 0, 0);
            }
        if (vrow) {
#pragma unroll
            for (int nt_ = 0; nt_ < 2; ++nt_) {
                int c_ = nt_ ? col1 : col0;
#pragma unroll
                for (int i_ = 0; i_ < 4; ++i_) {
                    int r_ = lkb * 4 + i_;
                    float g = sigm(ach[nt_][i_] + acl[nt_][i_] * 4.8828125e-4f);
                    float sv = g * nwv[nt_][i_] + (1.0f - g) * oval[nt_][i_];
                    stf[r_][c_] = sv;
                    WRHL(0, 1, r_, c_, sv);
                }
            }
        }
        __syncthreads();
    }
    for (int i = tid; i < NS * ND; i += 256)
        stout[(size_t)b * NS * ND + i] = stf[i >> 7][i & 127];
#undef LOADW
#undef LDA
#undef MM
#undef WRHL
}

// ---------------------------------------------------------------------------
// Kernel 3: out[b][o] = stflat[b] . Wout[o] + bout[o].  One wave per row.
// ---------------------------------------------------------------------------
__global__ __launch_bounds__(512) void k_out(
    const float* __restrict__ stflat, const float* __restrict__ Wout,
    const float* __restrict__ bout, float* __restrict__ out) {
    __shared__ float stl[NB][NS * ND];
    int tid = threadIdx.x;
    for (int idx = tid; idx < NB * NS * ND; idx += 512)
        stl[idx >> 10][idx & 1023] = stflat[idx];
    __syncthreads();
    int wave = tid >> 6, lane = tid & 63;
    int o = blockIdx.x * 8 + wave;
    float acc[NB];
#pragma unroll
    for (int b = 0; b < NB; ++b) acc[b] = 0.0f;
    const float4* wrow = (const float4*)(Wout + (size_t)o * (NS * ND));
#pragma unroll
    for (int i = 0; i < 4; ++i) {
        float4 wv = wrow[i * 64 + lane];
        int kb = (i * 64 + lane) * 4;
#pragma unroll
        for (int b = 0; b < NB; ++b) {
            float4 sv = *(const float4*)&stl[b][kb];
            acc[b] += dot4(wv, sv);
        }
    }
#pragma unroll
    for (int off = 32; off; off >>= 1) {
#pragma unroll
        for (int b = 0; b < NB; ++b) acc[b] += __shfl_down(acc[b], off);
    }
    if (lane == 0) {
        float bb = bout[o];
#pragma unroll
        for (int b = 0; b < NB; ++b) out[(size_t)b * NOUT + o] = acc[b] + bb;
    }
}

extern "C" void kernel_launch(void* const* d_in, const int* in_sizes, int n_in,
                              void* d_out, int out_size, void* d_ws, size_t ws_size,
                              hipStream_t stream) {
    const int* x = (const int*)d_in[0];
    const float* emb = (const float*)d_in[1];
    const float* init_states = (const float*)d_in[2];
    const float* Wz = (const float*)d_in[3];
    const float* bz = (const float*)d_in[4];
    const float* Wr = (const float*)d_in[5];
    const float* br = (const float*)d_in[6];
    const float* Wh = (const float*)d_in[7];
    const float* bh = (const float*)d_in[8];
    const float* Wq = (const float*)d_in[9];
    const float* bq = (const float*)d_in[10];
    const float* Wk = (const float*)d_in[11];
    const float* bk = (const float*)d_in[12];
    const float* Wv = (const float*)d_in[13];
    const float* bv = (const float*)d_in[14];
    const float* Wo = (const float*)d_in[15];
    const float* bo = (const float*)d_in[16];
    const float* Wc = (const float*)d_in[17];
    const float* bc = (const float*)d_in[18];
    const float* Wout = (const float*)d_in[19];
    const float* bout = (const float*)d_in[20];
    float* out = (float*)d_out;

    float* xproj = (float*)d_ws;                          // 8*1024*3*128 f32 = 12.58 MB
    float* stflat = xproj + (size_t)NB * NT * 3 * ND;     // 8192 f32
    _Float16* wpack = (_Float16*)(stflat + NB * NS * ND); // 9*16*256*8 f16 = 576 KB

    k_pack<<<144, 256, 0, stream>>>(Wz, Wr, Wh, Wq, Wk, Wv, Wo, Wc, wpack);
    k_embed_xproj<<<NB * NT, 128, 0, stream>>>(x, emb, Wz, bz, Wr, br, Wh, bh, xproj);
    k_scan<<<NB, 256, 0, stream>>>(xproj, init_states, wpack, bq, bk, bv, bo, bc, stflat);
    k_out<<<NOUT / 8, 512, 0, stream>>>(stflat, Wout, bout, out);
}

// Round 3
// 12218.716 us; speedup vs baseline: 10.6267x; 1.0615x over previous
//
#include <hip/hip_runtime.h>
#include <math.h>

#define NB 8
#define NT 1024
#define ND 128
#define NS 8
#define NH 4
#define NOUT 32000

typedef _Float16 f16x8 __attribute__((ext_vector_type(8)));
typedef _Float16 f16x4 __attribute__((ext_vector_type(4)));
typedef float f32x4 __attribute__((ext_vector_type(4)));

__device__ __forceinline__ float sigm(float x) { return 1.0f / (1.0f + __expf(-x)); }
__device__ __forceinline__ float ftanh(float x) {
    float ax = fabsf(x);
    float e = __expf(-2.0f * ax);
    float t = (1.0f - e) / (1.0f + e);
    return copysignf(t, x);
}
__device__ __forceinline__ float dot4(float4 a, float4 b) {
    return a.x * b.x + a.y * b.y + a.z * b.z + a.w * b.w;
}

// Raw barrier: LDS-visibility only (lgkmcnt(0) commits our ds_writes, barrier
// syncs). Register-destined global loads (weight streams, xp prefetch) stay
// in flight across it -- no vmcnt(0) drain like __syncthreads would emit.
#define BAR()                                              \
    {                                                      \
        asm volatile("s_waitcnt lgkmcnt(0)" ::: "memory"); \
        __builtin_amdgcn_s_barrier();                      \
        asm volatile("" ::: "memory");                     \
    }

// ---------------------------------------------------------------------------
// Kernel 0: pack the 9 weight matrices (state-side halves) into MFMA B-frag
// order as dual-fp16 (hi + lo*2^11).  Matrix m, frag f=(nt*4+kt)*2+pl,
// thread t=(w*64+lane): value = W[col][k], col=32w+nt*16+(lane&15),
// k = kt*32+8*(lane>>4)+i.  64 KB per matrix, 576 KB total (L2-resident).
// mats: 0 Wz_s, 1 Wr_s, 2 Wh_s, 3 Wq, 4 Wk, 5 Wv, 6 Wc_new, 7 Wo, 8 Wc_attn
// ---------------------------------------------------------------------------
__global__ __launch_bounds__(256) void k_pack(
    const float* __restrict__ Wz, const float* __restrict__ Wr, const float* __restrict__ Wh,
    const float* __restrict__ Wq, const float* __restrict__ Wk, const float* __restrict__ Wv,
    const float* __restrict__ Wo, const float* __restrict__ Wc, _Float16* __restrict__ wpack) {
    int linear = blockIdx.x * 256 + threadIdx.x;   // m*4096 + f*256 + t
    int m = linear >> 12;
    int f = (linear >> 8) & 15;
    int t = linear & 255;
    int nt = f >> 3, kt = (f >> 1) & 3, pl = f & 1;
    int w = t >> 6, lane = t & 63;
    int col = 32 * w + nt * 16 + (lane & 15);
    int kk = kt * 32 + 8 * (lane >> 4);
    const float* src;
    int stride, koff = 0;
    switch (m) {
        case 0: src = Wz; stride = 256; break;
        case 1: src = Wr; stride = 256; break;
        case 2: src = Wh; stride = 256; break;
        case 3: src = Wq; stride = 128; break;
        case 4: src = Wk; stride = 128; break;
        case 5: src = Wv; stride = 128; break;
        case 6: src = Wc; stride = 256; break;            // c1 (new part)
        case 7: src = Wo; stride = 128; break;
        default: src = Wc; stride = 256; koff = 128; break; // c2 (attn part)
    }
    const float* p = src + (size_t)col * stride + koff + kk;
    f16x8 out;
#pragma unroll
    for (int i = 0; i < 8; ++i) {
        float v = p[i];
        _Float16 h = (_Float16)v;
        out[i] = pl ? (_Float16)((v - (float)h) * 2048.0f) : h;
    }
    *(f16x8*)(wpack + (size_t)linear * 8) = out;
}

// ---------------------------------------------------------------------------
// Kernel 1: embedding gather + x-half of z/r/h gate preactivations (+bias)
// ---------------------------------------------------------------------------
__global__ __launch_bounds__(128) void k_embed_xproj(
    const int* __restrict__ x, const float* __restrict__ emb,
    const float* __restrict__ Wz, const float* __restrict__ bz,
    const float* __restrict__ Wr, const float* __restrict__ br,
    const float* __restrict__ Wh, const float* __restrict__ bh,
    float* __restrict__ xproj) {
    int bt = blockIdx.x;
    int j = threadIdx.x;
    __shared__ float xe[ND];
    long tok = (long)x[bt];
    xe[j] = emb[tok * ND + j];
    __syncthreads();
    const float4* xe4 = (const float4*)xe;
    const float4* wz = (const float4*)(Wz + j * 2 * ND + ND);
    const float4* wr = (const float4*)(Wr + j * 2 * ND + ND);
    const float4* wh = (const float4*)(Wh + j * 2 * ND + ND);
    float az = bz[j], ar = br[j], ah = bh[j];
#pragma unroll 8
    for (int k = 0; k < ND / 4; ++k) {
        float4 xv = xe4[k];
        az += dot4(wz[k], xv);
        ar += dot4(wr[k], xv);
        ah += dot4(wh[k], xv);
    }
    float* o = xproj + (long)bt * 3 * ND;
    o[j] = az;
    o[ND + j] = ar;
    o[2 * ND + j] = ah;
}

// ---------------------------------------------------------------------------
// Kernel 2: the scan.  1 block/batch, 256 threads (4 waves).
// Wave w owns output cols 32w..32w+31 and attention head w (fully wave-local
// attention -> no barriers in the QKV/attn phase).  z,r,h,q,k register-
// resident (320 VGPR); v,c1,o,c2 streamed through one rotating 64-VGPR
// buffer, each issued >=1 compute region before use.  Raw barriers (no vmcnt
// drain).  5 barriers/step.
// ---------------------------------------------------------------------------
__global__ __launch_bounds__(256, 1) void k_scan(
    const float* __restrict__ xproj, const float* __restrict__ init_states,
    const _Float16* __restrict__ wpack,
    const float* __restrict__ bq, const float* __restrict__ bk, const float* __restrict__ bv,
    const float* __restrict__ bo, const float* __restrict__ bc,
    float* __restrict__ stout) {
    const int b = blockIdx.x, tid = threadIdx.x;
    const int lane = tid & 63, w = tid >> 6;
    const int lrow = lane & 15, lkb = lane >> 4;
    const int col0 = 32 * w + lrow, col1 = col0 + 16;
    const bool vrow = (lkb < 2);  // C rows 4*lkb+i < 8 are the real states

    __shared__ float stf[NS][132];                 // fp32 state (padded stride)
    __shared__ float qf[NS][132], kf[NS][132], vf[NS][132];
    __shared__ float pf[NH][NS][NS];
    // fp16 planes [16][128], XOR-swizzled; rows 8..15 stay zero (M-padding).
    // 0 st_h,1 st_l,2 rs_h,3 rs_l,4 nw_h,5 nw_l,6 at_h,7 at_l,8 ao_h,9 ao_l
    __shared__ _Float16 hp[10][16 * 128];

    for (int i = tid; i < 10 * 2048; i += 256) ((_Float16*)hp)[i] = (_Float16)0.0f;
    for (int i = tid; i < NS * ND; i += 256) {
        int s = i >> 7, d = i & 127;
        float v = init_states[i];
        stf[s][d] = v;
        _Float16 h = (_Float16)v;
        _Float16 l = (_Float16)((v - (float)h) * 2048.0f);
        int off = (s * 256 + d * 2) ^ ((s & 7) << 4);
        *(_Float16*)((char*)hp[0] + off) = h;
        *(_Float16*)((char*)hp[1] + off) = l;
    }

#define LOADW(BH, BL, m)                                                           \
    {                                                                              \
        const _Float16* base_ = wpack + (size_t)(m)*4096 * 8;                      \
        _Pragma("unroll") for (int nt_ = 0; nt_ < 2; ++nt_)                        \
        _Pragma("unroll") for (int kt_ = 0; kt_ < 4; ++kt_) {                      \
            BH[nt_][kt_] = *(const f16x8*)(base_ + (((nt_ * 4 + kt_) * 2 + 0) * 256 + tid) * 8); \
            BL[nt_][kt_] = *(const f16x8*)(base_ + (((nt_ * 4 + kt_) * 2 + 1) * 256 + tid) * 8); \
        }                                                                          \
    }

#define LDA(ph, pl_)                                                               \
    {                                                                              \
        _Pragma("unroll") for (int kt_ = 0; kt_ < 4; ++kt_) {                      \
            int off_ = (lrow * 256 + kt_ * 64 + lkb * 16) ^ ((lrow & 7) << 4);     \
            ah[kt_] = *(const f16x8*)((const char*)(ph) + off_);                   \
            al[kt_] = *(const f16x8*)((const char*)(pl_) + off_);                  \
        }                                                                          \
    }

#define MM(res, BH, BL, i0, i1)                                                    \
    {                                                                              \
        _Pragma("unroll") for (int nt_ = 0; nt_ < 2; ++nt_) {                      \
            float init_ = nt_ ? (i1) : (i0);                                       \
            f32x4 xh_ = {init_, init_, init_, init_};                              \
            f32x4 xl_ = {0.f, 0.f, 0.f, 0.f};                                      \
            _Pragma("unroll") for (int kt_ = 0; kt_ < 4; ++kt_) {                  \
                xh_ = __builtin_amdgcn_mfma_f32_16x16x32_f16(ah[kt_], BH[nt_][kt_], xh_, 0, 0, 0); \
                xl_ = __builtin_amdgcn_mfma_f32_16x16x32_f16(al[kt_], BH[nt_][kt_], xl_, 0, 0, 0); \
                xl_ = __builtin_amdgcn_mfma_f32_16x16x32_f16(ah[kt_], BL[nt_][kt_], xl_, 0, 0, 0); \
            }                                                                      \
            _Pragma("unroll") for (int i_ = 0; i_ < 4; ++i_)                       \
                res[nt_][i_] = xh_[i_] + xl_[i_] * 4.8828125e-4f;                  \
        }                                                                          \
    }

#define WRHL(pih, pil, row_, col_, val_)                                           \
    {                                                                              \
        float v_ = (val_);                                                         \
        _Float16 h_ = (_Float16)v_;                                                \
        _Float16 l_ = (_Float16)((v_ - (float)h_) * 2048.0f);                      \
        int off_ = ((row_)*256 + (col_)*2) ^ (((row_)&7) << 4);                    \
        *(_Float16*)((char*)hp[pih] + off_) = h_;                                  \
        *(_Float16*)((char*)hp[pil] + off_) = l_;                                  \
    }

    // resident weights: z, r, h, q, k (320 VGPRs)
    f16x8 Bzh[2][4], Bzl[2][4], Brh[2][4], Brl[2][4], Bhh[2][4], Bhl[2][4];
    f16x8 Bqh[2][4], Bql[2][4], Bkh[2][4], Bkl[2][4];
    LOADW(Bzh, Bzl, 0);
    LOADW(Brh, Brl, 1);
    LOADW(Bhh, Bhl, 2);
    LOADW(Bqh, Bql, 3);
    LOADW(Bkh, Bkl, 4);
    // rotating stream buffer: v -> c1 -> o -> c2 -> v(next t) ...
    f16x8 Sh[2][4], Sl[2][4];
    LOADW(Sh, Sl, 5);  // v for t=0

    const float bqv0 = bq[col0], bqv1 = bq[col1];
    const float bkv0 = bk[col0], bkv1 = bk[col1];
    const float bvv0 = bv[col0], bvv1 = bv[col1];
    const float bov0 = bo[col0], bov1 = bo[col1];
    const float bcv0 = bc[col0], bcv1 = bc[col1];

    f16x8 ah[4], al[4];
    float zv[2][4], nwv[2][4], oval[2][4];
    f32x4 ach[2], acl[2];

    // xp prefetch for t=0
    float xz0, xz1, xr0, xr1, xh0, xh1;
    {
        const float* xp = xproj + ((size_t)(b * NT)) * 3 * ND;
        xz0 = xp[col0]; xz1 = xp[col1];
        xr0 = xp[128 + col0]; xr1 = xp[128 + col1];
        xh0 = xp[256 + col0]; xh1 = xp[256 + col1];
    }

    BAR();

    for (int t = 0; t < NT; ++t) {
        // ---- phase A: z, r (resident), r*state ----
        LDA(hp[0], hp[1]);
        float zp[2][4], rp[2][4];
        MM(zp, Bzh, Bzl, xz0, xz1);
        MM(rp, Brh, Brl, xr0, xr1);
#pragma unroll
        for (int nt_ = 0; nt_ < 2; ++nt_)
#pragma unroll
            for (int i_ = 0; i_ < 4; ++i_) zv[nt_][i_] = sigm(zp[nt_][i_]);
        if (vrow) {
#pragma unroll
            for (int nt_ = 0; nt_ < 2; ++nt_) {
                int c_ = nt_ ? col1 : col0;
#pragma unroll
                for (int i_ = 0; i_ < 4; ++i_) {
                    int r_ = lkb * 4 + i_;
                    float rs_ = sigm(rp[nt_][i_]) * stf[r_][c_];
                    WRHL(2, 3, r_, c_, rs_);
                }
            }
        }
        BAR();
        // ---- phase B: cand/new (resident h) ----
        LDA(hp[2], hp[3]);
        float hpre[2][4];
        MM(hpre, Bhh, Bhl, xh0, xh1);
        if (vrow) {
#pragma unroll
            for (int nt_ = 0; nt_ < 2; ++nt_) {
                int c_ = nt_ ? col1 : col0;
#pragma unroll
                for (int i_ = 0; i_ < 4; ++i_) {
                    int r_ = lkb * 4 + i_;
                    float cand = ftanh(hpre[nt_][i_]);
                    float z = zv[nt_][i_];
                    float nv = (1.0f - z) * stf[r_][c_] + z * cand;
                    nwv[nt_][i_] = nv;
                    WRHL(4, 5, r_, c_, nv);
                }
            }
        }
        BAR();
        // ---- phase C: QKV + attention + C1 (all wave-local, no barriers) ----
        LDA(hp[4], hp[5]);  // ah/al = nw fragments, reused for q,k,v,c1
        {
            float qp_[2][4];
            MM(qp_, Bqh, Bql, bqv0, bqv1);
            if (vrow) {
#pragma unroll
                for (int nt_ = 0; nt_ < 2; ++nt_) {
                    int c_ = nt_ ? col1 : col0;
#pragma unroll
                    for (int i_ = 0; i_ < 4; ++i_) qf[lkb * 4 + i_][c_] = qp_[nt_][i_];
                }
            }
            float kp_[2][4];
            MM(kp_, Bkh, Bkl, bkv0, bkv1);
            if (vrow) {
#pragma unroll
                for (int nt_ = 0; nt_ < 2; ++nt_) {
                    int c_ = nt_ ? col1 : col0;
#pragma unroll
                    for (int i_ = 0; i_ < 4; ++i_) kf[lkb * 4 + i_][c_] = kp_[nt_][i_];
                }
            }
            float vp_[2][4];
            MM(vp_, Sh, Sl, bvv0, bvv1);  // S = v
            if (vrow) {
#pragma unroll
                for (int nt_ = 0; nt_ < 2; ++nt_) {
                    int c_ = nt_ ? col1 : col0;
#pragma unroll
                    for (int i_ = 0; i_ < 4; ++i_) vf[lkb * 4 + i_][c_] = vp_[nt_][i_];
                }
            }
        }
        LOADW(Sh, Sl, 6);  // stream c1
        // scores + softmax (wave w == head w), fp32 VALU, wave-local
        {
            int sq = lane >> 3, skv = lane & 7;
            float s_ = 0.f;
#pragma unroll
            for (int j = 0; j < 8; ++j) {
                float4 qv = *(const float4*)&qf[sq][32 * w + 4 * j];
                float4 kv4 = *(const float4*)&kf[skv][32 * w + 4 * j];
                s_ += dot4(qv, kv4);
            }
            s_ *= 0.17677669529663687f;
            float mx = s_;
            mx = fmaxf(mx, __shfl_xor(mx, 1));
            mx = fmaxf(mx, __shfl_xor(mx, 2));
            mx = fmaxf(mx, __shfl_xor(mx, 4));
            float e_ = __expf(s_ - mx);
            float sm = e_;
            sm += __shfl_xor(sm, 1);
            sm += __shfl_xor(sm, 2);
            sm += __shfl_xor(sm, 4);
            pf[w][sq][skv] = e_ / sm;
        }
        // c1 accumulate (S = c1; ah/al still nw fragments)
#pragma unroll
        for (int nt_ = 0; nt_ < 2; ++nt_) {
            float init_ = nt_ ? bcv1 : bcv0;
            ach[nt_] = (f32x4){init_, init_, init_, init_};
            acl[nt_] = (f32x4){0.f, 0.f, 0.f, 0.f};
#pragma unroll
            for (int kt_ = 0; kt_ < 4; ++kt_) {
                ach[nt_] = __builtin_amdgcn_mfma_f32_16x16x32_f16(ah[kt_], Sh[nt_][kt_], ach[nt_], 0, 0, 0);
                acl[nt_] = __builtin_amdgcn_mfma_f32_16x16x32_f16(al[kt_], Sh[nt_][kt_], acl[nt_], 0, 0, 0);
                acl[nt_] = __builtin_amdgcn_mfma_f32_16x16x32_f16(ah[kt_], Sl[nt_][kt_], acl[nt_], 0, 0, 0);
            }
        }
        LOADW(Sh, Sl, 7);  // stream o
        // PV: att = p @ v  -> at planes (dual fp16), wave-local
        {
            int pq = lane >> 3, dq = lane & 7;
            int dcol = 32 * w + dq * 4;
            float avx = 0.f, avy = 0.f, avz = 0.f, avw = 0.f;
#pragma unroll
            for (int kv2 = 0; kv2 < 8; ++kv2) {
                float pp = pf[w][pq][kv2];
                float4 vv4 = *(const float4*)&vf[kv2][dcol];
                avx += pp * vv4.x;
                avy += pp * vv4.y;
                avz += pp * vv4.z;
                avw += pp * vv4.w;
            }
            float vals[4] = {avx, avy, avz, avw};
            f16x4 hv, lv;
#pragma unroll
            for (int i_ = 0; i_ < 4; ++i_) {
                _Float16 h_ = (_Float16)vals[i_];
                hv[i_] = h_;
                lv[i_] = (_Float16)((vals[i_] - (float)h_) * 2048.0f);
            }
            int off_ = (pq * 256 + dcol * 2) ^ ((pq & 7) << 4);
            *(f16x4*)((char*)hp[6] + off_) = hv;
            *(f16x4*)((char*)hp[7] + off_) = lv;
        }
        BAR();
        // ---- phase D: O projection (S = o) ----
        LDA(hp[6], hp[7]);
        MM(oval, Sh, Sl, bov0, bov1);
        if (vrow) {
#pragma unroll
            for (int nt_ = 0; nt_ < 2; ++nt_) {
                int c_ = nt_ ? col1 : col0;
#pragma unroll
                for (int i_ = 0; i_ < 4; ++i_) WRHL(8, 9, lkb * 4 + i_, c_, oval[nt_][i_]);
            }
        }
        LOADW(Sh, Sl, 8);  // stream c2
        BAR();
        // ---- phase E: C2 + gate blend -> new state ----
        LDA(hp[8], hp[9]);
#pragma unroll
        for (int nt_ = 0; nt_ < 2; ++nt_)
#pragma unroll
            for (int kt_ = 0; kt_ < 4; ++kt_) {
                ach[nt_] = __builtin_amdgcn_mfma_f32_16x16x32_f16(ah[kt_], Sh[nt_][kt_], ach[nt_], 0, 0, 0);
                acl[nt_] = __builtin_amdgcn_mfma_f32_16x16x32_f16(al[kt_], Sh[nt_][kt_], acl[nt_], 0, 0, 0);
                acl[nt_] = __builtin_amdgcn_mfma_f32_16x16x32_f16(ah[kt_], Sl[nt_][kt_], acl[nt_], 0, 0, 0);
            }
        if (vrow) {
#pragma unroll
            for (int nt_ = 0; nt_ < 2; ++nt_) {
                int c_ = nt_ ? col1 : col0;
#pragma unroll
                for (int i_ = 0; i_ < 4; ++i_) {
                    int r_ = lkb * 4 + i_;
                    float g = sigm(ach[nt_][i_] + acl[nt_][i_] * 4.8828125e-4f);
                    float sv = g * nwv[nt_][i_] + (1.0f - g) * oval[nt_][i_];
                    stf[r_][c_] = sv;
                    WRHL(0, 1, r_, c_, sv);
                }
            }
        }
        LOADW(Sh, Sl, 5);  // stream v for t+1 (dead-load on last iter, harmless)
        {
            int tn = (t + 1 < NT) ? t + 1 : t;
            const float* xpn = xproj + ((size_t)(b * NT + tn)) * 3 * ND;
            xz0 = xpn[col0]; xz1 = xpn[col1];
            xr0 = xpn[128 + col0]; xr1 = xpn[128 + col1];
            xh0 = xpn[256 + col0]; xh1 = xpn[256 + col1];
        }
        BAR();
    }
    for (int i = tid; i < NS * ND; i += 256)
        stout[(size_t)b * NS * ND + i] = stf[i >> 7][i & 127];
#undef LOADW
#undef LDA
#undef MM
#undef WRHL
}

// ---------------------------------------------------------------------------
// Kernel 3: out[b][o] = stflat[b] . Wout[o] + bout[o].  One wave per row.
// ---------------------------------------------------------------------------
__global__ __launch_bounds__(512) void k_out(
    const float* __restrict__ stflat, const float* __restrict__ Wout,
    const float* __restrict__ bout, float* __restrict__ out) {
    __shared__ float stl[NB][NS * ND];
    int tid = threadIdx.x;
    for (int idx = tid; idx < NB * NS * ND; idx += 512)
        stl[idx >> 10][idx & 1023] = stflat[idx];
    __syncthreads();
    int wave = tid >> 6, lane = tid & 63;
    int o = blockIdx.x * 8 + wave;
    float acc[NB];
#pragma unroll
    for (int b = 0; b < NB; ++b) acc[b] = 0.0f;
    const float4* wrow = (const float4*)(Wout + (size_t)o * (NS * ND));
#pragma unroll
    for (int i = 0; i < 4; ++i) {
        float4 wv = wrow[i * 64 + lane];
        int kb = (i * 64 + lane) * 4;
#pragma unroll
        for (int b = 0; b < NB; ++b) {
            float4 sv = *(const float4*)&stl[b][kb];
            acc[b] += dot4(wv, sv);
        }
    }
#pragma unroll
    for (int off = 32; off; off >>= 1) {
#pragma unroll
        for (int b = 0; b < NB; ++b) acc[b] += __shfl_down(acc[b], off);
    }
    if (lane == 0) {
        float bb = bout[o];
#pragma unroll
        for (int b = 0; b < NB; ++b) out[(size_t)b * NOUT + o] = acc[b] + bb;
    }
}

extern "C" void kernel_launch(void* const* d_in, const int* in_sizes, int n_in,
                              void* d_out, int out_size, void* d_ws, size_t ws_size,
                              hipStream_t stream) {
    const int* x = (const int*)d_in[0];
    const float* emb = (const float*)d_in[1];
    const float* init_states = (const float*)d_in[2];
    const float* Wz = (const float*)d_in[3];
    const float* bz = (const float*)d_in[4];
    const float* Wr = (const float*)d_in[5];
    const float* br = (const float*)d_in[6];
    const float* Wh = (const float*)d_in[7];
    const float* bh = (const float*)d_in[8];
    const float* Wq = (const float*)d_in[9];
    const float* bq = (const float*)d_in[10];
    const float* Wk = (const float*)d_in[11];
    const float* bk = (const float*)d_in[12];
    const float* Wv = (const float*)d_in[13];
    const float* bv = (const float*)d_in[14];
    const float* Wo = (const float*)d_in[15];
    const float* bo = (const float*)d_in[16];
    const float* Wc = (const float*)d_in[17];
    const float* bc = (const float*)d_in[18];
    const float* Wout = (const float*)d_in[19];
    const float* bout = (const float*)d_in[20];
    float* out = (float*)d_out;

    float* xproj = (float*)d_ws;                          // 8*1024*3*128 f32 = 12.58 MB
    float* stflat = xproj + (size_t)NB * NT * 3 * ND;     // 8192 f32
    _Float16* wpack = (_Float16*)(stflat + NB * NS * ND); // 9*16*256*8 f16 = 576 KB

    k_pack<<<144, 256, 0, stream>>>(Wz, Wr, Wh, Wq, Wk, Wv, Wo, Wc, wpack);
    k_embed_xproj<<<NB * NT, 128, 0, stream>>>(x, emb, Wz, bz, Wr, br, Wh, bh, xproj);
    k_scan<<<NB, 256, 0, stream>>>(xproj, init_states, wpack, bq, bk, bv, bo, bc, stflat);
    k_out<<<NOUT / 8, 512, 0, stream>>>(stflat, Wout, bout, out);
}